// Round 4
// baseline (260.049 us; speedup 1.0000x reference)
//
#include <hip/hip_runtime.h>

// Problem constants (from reference setup_inputs): B=8, H=512, W=512, C=16.
// dense_image_warp: out[b,h,w,c] = bilinear(img, h - flow[b,h,w,0], w - flow[b,h,w,1])
// tfa semantics: floor clipped to [0, size-2], alpha clipped to [0,1].
//
// R4 design: one 8x8 output tile per 256-thread block (1 pixel per 4-lane
// quad, 16 B channels/lane). Tile+margin gather footprint (~25 KB) fits L1;
// XCD-batch swizzle (b = blockIdx & 7) keeps each XCD's L2 on one batch image.

constexpr int B = 8;
constexpr int H = 512;
constexpr int W = 512;
constexpr int C = 16;
constexpr int TILE = 8;  // 8x8 pixels per block

// Native clang vector types — required by __builtin_nontemporal_*.
typedef float vf2 __attribute__((ext_vector_type(2)));
typedef float vf4 __attribute__((ext_vector_type(4)));

__global__ __launch_bounds__(256, 8) void warp_kernel(
    const float* __restrict__ img,
    const float* __restrict__ flow,
    float* __restrict__ out)
{
    // blockIdx -> (batch, tileY, tileX); batch in low 3 bits so round-robin
    // XCD dispatch gives each XCD one batch's image in its L2.
    const int bid = blockIdx.x;
    const int b  = bid & 7;
    const int t  = bid >> 3;           // 0 .. 4095
    const int h0 = (t >> 6) << 3;      // tile origin row
    const int w0 = (t & 63) << 3;      // tile origin col

    const int quad = threadIdx.x >> 2; // 0..63 -> pixel within tile
    const int c0   = (threadIdx.x & 3) << 2;  // channel offset 0,4,8,12

    const int h = h0 + (quad >> 3);
    const int w = w0 + (quad & 7);
    const size_t p = ((size_t)(b * H + h)) * W + w;

    // flow[b,h,w,{0,1}] — same address across the quad (broadcast); read-once.
    const vf2 f = __builtin_nontemporal_load(
        reinterpret_cast<const vf2*>(flow + 2 * p));

    const float qy = (float)h - f.x;
    const float qx = (float)w - f.y;

    const float fy = fminf(fmaxf(floorf(qy), 0.0f), (float)(H - 2));
    const float fx = fminf(fmaxf(floorf(qx), 0.0f), (float)(W - 2));
    const float ay = fminf(fmaxf(qy - fy, 0.0f), 1.0f);
    const float ax = fminf(fmaxf(qx - fx, 0.0f), 1.0f);
    const int iy = (int)fy;
    const int ix = (int)fx;

    const size_t rowStride = (size_t)W * C;
    const float* base = img + ((size_t)((b * H + iy) * W + ix) * C + c0);

    // 4 corner gathers: each is one 64-B line for the quad (4 lanes x 16 B).
    const vf4 tl = *reinterpret_cast<const vf4*>(base);
    const vf4 tr = *reinterpret_cast<const vf4*>(base + C);
    const vf4 bl = *reinterpret_cast<const vf4*>(base + rowStride);
    const vf4 br = *reinterpret_cast<const vf4*>(base + rowStride + C);

    // Reference operation order: lerp in x on top/bottom, then lerp in y.
    const vf4 tv = tl + ax * (tr - tl);
    const vf4 bv = bl + ax * (br - bl);
    const vf4 o  = tv + ay * (bv - tv);

    // write-once stream -> nontemporal (don't pollute L1/L2)
    __builtin_nontemporal_store(
        o, reinterpret_cast<vf4*>(out + p * C + c0));
}

extern "C" void kernel_launch(void* const* d_in, const int* in_sizes, int n_in,
                              void* d_out, int out_size, void* d_ws, size_t ws_size,
                              hipStream_t stream) {
    const float* img  = (const float*)d_in[0];   // [B,H,W,C] fp32
    const float* flow = (const float*)d_in[1];   // [B,H,W,2] fp32
    float* out = (float*)d_out;                  // [B,H,W,C] fp32

    // B * (H/TILE) * (W/TILE) = 8 * 64 * 64 = 32768 blocks, 256 threads each
    const int grid = B * (H / TILE) * (W / TILE);
    warp_kernel<<<grid, 256, 0, stream>>>(img, flow, out);
}